// Round 6
// baseline (323.928 us; speedup 1.0000x reference)
//
#include <hip/hip_runtime.h>
#include <cstdint>
#include <cstddef>

#define GN 16384          // nodes
#define GF 64             // features
#define NW (GN / 32)      // 512 dwords per packed bit-row

typedef __bf16 bf16x8 __attribute__((ext_vector_type(8)));
typedef float f32x4 __attribute__((ext_vector_type(4)));
typedef unsigned int u32x4 __attribute__((ext_vector_type(4)));

// R2-validated cheap decode: t = (b&0xff)*0x8001 places bit i at {i, i+15};
// ((t>>2d) & 0x10001) * 0x3F80 -> dword d = bf16 pair {bit 2d, bit 2d+1}.
// All muls fit u24; no cross-field carries (0x3F80 < 2^16).
__device__ __forceinline__ bf16x8 decode8(unsigned int b) {
  unsigned int t = (b & 0xffu) * 0x8001u;
  u32x4 r;
  r[0] = (t & 0x00010001u) * 0x3F80u;
  r[1] = ((t >> 2) & 0x00010001u) * 0x3F80u;
  r[2] = ((t >> 4) & 0x00010001u) * 0x3F80u;
  r[3] = ((t >> 6) & 0x00010001u) * 0x3F80u;
  return __builtin_bit_cast(bf16x8, r);
}

__device__ __forceinline__ unsigned short f2bf(float v) {  // RNE f32->bf16
  unsigned int u = __builtin_bit_cast(unsigned int, v);
  u += 0x7fffu + ((u >> 16) & 1u);
  return (unsigned short)(u >> 16);
}

__device__ __forceinline__ float bf2f(unsigned short s) {
  return __builtin_bit_cast(float, (unsigned int)s << 16);
}

// ---------------------------------------------------------------------------
// K1 v2: same reads/stores/math as R1, regridded for occupancy.
// 2048 blocks = 16 col-blocks x 128 row-blocks; block = 1024 cols x 128 rows.
// 8 blocks/CU -> enough waves to satisfy Little's law on HBM latency.
// ---------------------------------------------------------------------------
__global__ __launch_bounds__(256) void k_pack(const float* __restrict__ adj,
                                              float* __restrict__ deg,
                                              unsigned int* __restrict__ packed) {
  const int cb = blockIdx.x >> 7;      // 0..15   (1024-column slice)
  const int jb = blockIdx.x & 127;     // 0..127  (128-row slab)
  const int col0 = cb * 1024 + threadIdx.x * 4;
  const int j0 = jb * 128;
  int cnt0 = 0, cnt1 = 0, cnt2 = 0, cnt3 = 0;

  u32x4 v0, v1, v2, v3;
#pragma unroll
  for (int q = 0; q < 4; ++q) {        // 32 rows per word
    unsigned int w0 = 0, w1 = 0, w2 = 0, w3 = 0;
    const float* base = adj + (size_t)(j0 + q * 32) * GN + col0;
#pragma unroll 8
    for (int b = 0; b < 32; ++b) {
      f32x4 a = *(const f32x4*)(base + (size_t)b * GN);
      unsigned int m = 1u << b;
      if (a.x != 0.f) w0 |= m;
      if (a.y != 0.f) w1 |= m;
      if (a.z != 0.f) w2 |= m;
      if (a.w != 0.f) w3 |= m;
    }
    v0[q] = w0; v1[q] = w1; v2[q] = w2; v3[q] = w3;
    cnt0 += __popc(w0); cnt1 += __popc(w1); cnt2 += __popc(w2); cnt3 += __popc(w3);
  }
  const size_t wbase = (size_t)jb * 4;
  *(u32x4*)(packed + (size_t)(col0 + 0) * NW + wbase) = v0;
  *(u32x4*)(packed + (size_t)(col0 + 1) * NW + wbase) = v1;
  *(u32x4*)(packed + (size_t)(col0 + 2) * NW + wbase) = v2;
  *(u32x4*)(packed + (size_t)(col0 + 3) * NW + wbase) = v3;

  atomicAdd(&deg[col0 + 0], (float)cnt0);
  atomicAdd(&deg[col0 + 1], (float)cnt1);
  atomicAdd(&deg[col0 + 2], (float)cnt2);
  atomicAdd(&deg[col0 + 3], (float)cnt3);
}

// ---------------------------------------------------------------------------
// K2 (byte-identical to R4/R5): z = dinv*(x@W); z row-major bf16 + chunked z2.
// Z2[jc][f][jj]: 4 KB chunk = 64 features x 32 nodes contiguous.
// ---------------------------------------------------------------------------
__global__ __launch_bounds__(256) void k_z(const float* __restrict__ x,
                                           const float* __restrict__ W,
                                           const float* __restrict__ deg,
                                           float* __restrict__ dinv,
                                           unsigned short* __restrict__ z_rm,
                                           unsigned short* __restrict__ z2) {
  __shared__ float Wl[64][64];
  __shared__ float xl[64][64];
  const int tid = threadIdx.x;
  const int f = tid & 63;
  const int w = tid >> 6;
  const int rowB = blockIdx.x * 64;

  for (int idx = tid; idx < 4096; idx += 256) {
    Wl[idx >> 6][idx & 63] = W[idx];
    xl[idx >> 6][idx & 63] = x[(size_t)rowB * 64 + idx];
  }
  __syncthreads();

  float acc[16];
#pragma unroll
  for (int r = 0; r < 16; ++r) acc[r] = 0.f;
  for (int k = 0; k < 64; ++k) {
    float wk = Wl[k][f];
#pragma unroll
    for (int r = 0; r < 16; ++r) acc[r] = fmaf(xl[w * 16 + r][k], wk, acc[r]);
  }

  const int row0 = rowB + w * 16;
  if (f < 16) {
    int row = row0 + f;
    dinv[row] = 1.0f / sqrtf(deg[row] + 1.0f);
  }

  unsigned short zs[16];
#pragma unroll
  for (int r = 0; r < 16; ++r) {
    int row = row0 + r;
    float di = 1.0f / sqrtf(deg[row] + 1.0f);
    unsigned short zb = f2bf(di * acc[r]);
    zs[r] = zb;
    z_rm[(size_t)row * GF + f] = zb;
  }
  unsigned int p[8];
#pragma unroll
  for (int i = 0; i < 8; ++i)
    p[i] = (unsigned int)zs[2 * i] | ((unsigned int)zs[2 * i + 1] << 16);
  char* dst = (char*)z2 + (size_t)((rowB >> 5) + (w >> 1)) * 4096 + f * 64 + (w & 1) * 32;
  u32x4 lo = {p[0], p[1], p[2], p[3]};
  u32x4 hi = {p[4], p[5], p[6], p[7]};
  *(u32x4*)dst = lo;
  *(u32x4*)(dst + 16) = hi;
}

// ---------------------------------------------------------------------------
// K3 v4: COLUMN-SPLIT for occupancy. 512 thr = 8 waves = 4 K-quarters x 2
// col-halves. Per wave/step: 4 A-decodes + 8 MFMA + 2 z-loads. Per-block z2
// traffic UNCHANGED vs v3 (each col-half reads only its half-chunk), but
// 2 waves/SIMD now interleave to fill VALU/MFMA dependency bubbles.
// Keeps R5's 1-chunk-deep z prefetch + 1-iter bits prefetch.
// ---------------------------------------------------------------------------
__global__ __launch_bounds__(512) void k_spmm(const unsigned int* __restrict__ packed,
                                              const unsigned short* __restrict__ z2,
                                              const unsigned short* __restrict__ z_rm,
                                              const float* __restrict__ dinv,
                                              const float* __restrict__ bias,
                                              float* __restrict__ out) {
  __shared__ float red[4][64][64];  // [kq][row][col], 64 KB
  const int i0 = blockIdx.x * 64;
  const int tid = threadIdx.x;
  const int wid = tid >> 6, lane = tid & 63;
  const int kq = wid & 3, h = wid >> 2;      // K-quarter, column-half
  const int lrow = lane & 15, kb = lane >> 4;
  const int sh = kb * 8;

  f32x4 acc[4][2];
#pragma unroll
  for (int m = 0; m < 4; ++m)
#pragma unroll
    for (int n = 0; n < 2; ++n) acc[m][n] = (f32x4){0.f, 0.f, 0.f, 0.f};

  const unsigned int* pr0 = packed + (size_t)(i0 + 0 * 16 + lrow) * NW + kq * 128;
  const unsigned int* pr1 = packed + (size_t)(i0 + 1 * 16 + lrow) * NW + kq * 128;
  const unsigned int* pr2 = packed + (size_t)(i0 + 2 * 16 + lrow) * NW + kq * 128;
  const unsigned int* pr3 = packed + (size_t)(i0 + 3 * 16 + lrow) * NW + kq * 128;
  // col = h*32 + n*16 + lrow; byte in chunk = col*64 + kb*16.
  const char* zbase = (const char*)z2 + (size_t)(kq * 128) * 4096 +
                      h * 2048 + lrow * 64 + kb * 16;

  // pipeline prologue
  bf16x8 cur0 = *(const bf16x8*)(zbase + 0 * 1024);
  bf16x8 cur1 = *(const bf16x8*)(zbase + 1 * 1024);
  u32x4 bits0 = *(const u32x4*)pr0;
  u32x4 bits1 = *(const u32x4*)pr1;
  u32x4 bits2 = *(const u32x4*)pr2;
  u32x4 bits3 = *(const u32x4*)pr3;

  for (int it = 0; it < 32; ++it) {
    // bits prefetch, one iteration ahead (tail lands in 64 B ws slack)
    u32x4 nb0 = *(const u32x4*)(pr0 + 4);
    u32x4 nb1 = *(const u32x4*)(pr1 + 4);
    u32x4 nb2 = *(const u32x4*)(pr2 + 4);
    u32x4 nb3 = *(const u32x4*)(pr3 + 4);
#pragma unroll
    for (int s = 0; s < 4; ++s) {
      // z prefetch: next chunk's two half-fragments (tail reads land in
      // the adjacent mapped `packed` buffer - values never consumed)
      const char* zn = zbase + (s + 1) * 4096;
      bf16x8 n0 = *(const bf16x8*)(zn + 0 * 1024);
      bf16x8 n1 = *(const bf16x8*)(zn + 1 * 1024);

      bf16x8 a0 = decode8(bits0[s] >> sh);
      acc[0][0] = __builtin_amdgcn_mfma_f32_16x16x32_bf16(a0, cur0, acc[0][0], 0, 0, 0);
      acc[0][1] = __builtin_amdgcn_mfma_f32_16x16x32_bf16(a0, cur1, acc[0][1], 0, 0, 0);
      bf16x8 a1 = decode8(bits1[s] >> sh);
      acc[1][0] = __builtin_amdgcn_mfma_f32_16x16x32_bf16(a1, cur0, acc[1][0], 0, 0, 0);
      acc[1][1] = __builtin_amdgcn_mfma_f32_16x16x32_bf16(a1, cur1, acc[1][1], 0, 0, 0);
      bf16x8 a2 = decode8(bits2[s] >> sh);
      acc[2][0] = __builtin_amdgcn_mfma_f32_16x16x32_bf16(a2, cur0, acc[2][0], 0, 0, 0);
      acc[2][1] = __builtin_amdgcn_mfma_f32_16x16x32_bf16(a2, cur1, acc[2][1], 0, 0, 0);
      bf16x8 a3 = decode8(bits3[s] >> sh);
      acc[3][0] = __builtin_amdgcn_mfma_f32_16x16x32_bf16(a3, cur0, acc[3][0], 0, 0, 0);
      acc[3][1] = __builtin_amdgcn_mfma_f32_16x16x32_bf16(a3, cur1, acc[3][1], 0, 0, 0);

      cur0 = n0; cur1 = n1;
    }
    bits0 = nb0; bits1 = nb1; bits2 = nb2; bits3 = nb3;
    pr0 += 4; pr1 += 4; pr2 += 4; pr3 += 4;
    zbase += 16384;  // 4 chunks
  }

  // split-K partials: row = m*16 + kb*4 + r, col = h*32 + n*16 + lrow
#pragma unroll
  for (int m = 0; m < 4; ++m)
#pragma unroll
    for (int n = 0; n < 2; ++n)
#pragma unroll
      for (int r = 0; r < 4; ++r)
        red[kq][m * 16 + kb * 4 + r][h * 32 + n * 16 + lrow] = acc[m][n][r];
  __syncthreads();

  // epilogue: reduce 4 partials, add self-loop z, scale, bias, relu
  const int c = tid & 63;
  const int rg = tid >> 6;  // 0..7
  const float bc = bias[c];
#pragma unroll
  for (int rr = 0; rr < 8; ++rr) {
    int r = rg * 8 + rr;
    int i = i0 + r;
    float s = red[0][r][c] + red[1][r][c] + red[2][r][c] + red[3][r][c];
    float o = dinv[i] * (s + bf2f(z_rm[(size_t)i * GF + c])) + bc;
    out[(size_t)i * GF + c] = fmaxf(o, 0.f);
  }
}

// ---------------------------------------------------------------------------
extern "C" void kernel_launch(void* const* d_in, const int* in_sizes, int n_in,
                              void* d_out, int out_size, void* d_ws, size_t ws_size,
                              hipStream_t stream) {
  const float* x = (const float*)d_in[0];
  const float* adj = (const float*)d_in[1];
  const float* W = (const float*)d_in[2];
  const float* bias = (const float*)d_in[3];
  float* out = (float*)d_out;

  char* ws = (char*)d_ws;
  float* deg = (float*)ws;                                        // 64 KB
  float* dinv = (float*)(ws + 65536);                             // 64 KB
  unsigned short* z_rm = (unsigned short*)(ws + 131072);          // 2 MB
  unsigned short* z2 = (unsigned short*)(ws + 131072 + 2097152);  // 2 MB chunk-tiled
  unsigned int* packed = (unsigned int*)(ws + 131072 + 4194304);  // 32 MB + 64 B slack
  if (ws_size < 37879872u) return;

  hipMemsetAsync(deg, 0, GN * sizeof(float), stream);
  k_pack<<<dim3(2048), dim3(256), 0, stream>>>(adj, deg, packed);
  k_z<<<dim3(GN / 64), dim3(256), 0, stream>>>(x, W, deg, dinv, z_rm, z2);
  k_spmm<<<dim3(GN / 64), dim3(512), 0, stream>>>(packed, z2, z_rm, dinv, bias, out);
}

// Round 7
// 264.785 us; speedup vs baseline: 1.2234x; 1.2234x over previous
//
#include <hip/hip_runtime.h>
#include <cstdint>
#include <cstddef>

#define GN 16384          // nodes
#define GF 64             // features
#define NW (GN / 32)      // 512 dwords per packed bit-row

typedef __bf16 bf16x8 __attribute__((ext_vector_type(8)));
typedef float f32x4 __attribute__((ext_vector_type(4)));
typedef unsigned int u32x4 __attribute__((ext_vector_type(4)));

// R2/R6-validated cheap decode: t = (b&0xff)*0x8001 places bit i at {i,i+15};
// ((t>>2d) & 0x10001) * 0x3F80 -> dword d = bf16 pair {bit 2d, bit 2d+1}.
__device__ __forceinline__ bf16x8 decode8(unsigned int b) {
  unsigned int t = (b & 0xffu) * 0x8001u;
  u32x4 r;
  r[0] = (t & 0x00010001u) * 0x3F80u;
  r[1] = ((t >> 2) & 0x00010001u) * 0x3F80u;
  r[2] = ((t >> 4) & 0x00010001u) * 0x3F80u;
  r[3] = ((t >> 6) & 0x00010001u) * 0x3F80u;
  return __builtin_bit_cast(bf16x8, r);
}

__device__ __forceinline__ unsigned short f2bf(float v) {  // RNE f32->bf16
  unsigned int u = __builtin_bit_cast(unsigned int, v);
  u += 0x7fffu + ((u >> 16) & 1u);
  return (unsigned short)(u >> 16);
}

__device__ __forceinline__ float bf2f(unsigned short s) {
  return __builtin_bit_cast(float, (unsigned int)s << 16);
}

// ---------------------------------------------------------------------------
// K1 v3: R1's 512-block structure (known 228 us), ONE change: packed words are
// buffered in registers across segs and each column's 64 B is stored
// contiguously at the end (4 back-to-back 16 B stores -> single line flush,
// kills partial-line write amplification).
// ---------------------------------------------------------------------------
__global__ __launch_bounds__(256) void k_pack(const float* __restrict__ adj,
                                              float* __restrict__ deg,
                                              unsigned int* __restrict__ packed) {
  const int cb = blockIdx.x >> 5;
  const int jb = blockIdx.x & 31;
  const int col0 = cb * 1024 + threadIdx.x * 4;
  const int j0 = jb * 512;
  int cnt0 = 0, cnt1 = 0, cnt2 = 0, cnt3 = 0;

  u32x4 vv0[4], vv1[4], vv2[4], vv3[4];  // [seg], fully unrolled -> registers

#pragma unroll
  for (int seg = 0; seg < 4; ++seg) {
#pragma unroll
    for (int q = 0; q < 4; ++q) {
      unsigned int w0 = 0, w1 = 0, w2 = 0, w3 = 0;
      const float* base = adj + (size_t)(j0 + seg * 128 + q * 32) * GN + col0;
#pragma unroll 8
      for (int b = 0; b < 32; ++b) {
        f32x4 a = *(const f32x4*)(base + (size_t)b * GN);
        unsigned int m = 1u << b;
        if (a.x != 0.f) w0 |= m;
        if (a.y != 0.f) w1 |= m;
        if (a.z != 0.f) w2 |= m;
        if (a.w != 0.f) w3 |= m;
      }
      vv0[seg][q] = w0; vv1[seg][q] = w1; vv2[seg][q] = w2; vv3[seg][q] = w3;
      cnt0 += __popc(w0); cnt1 += __popc(w1); cnt2 += __popc(w2); cnt3 += __popc(w3);
    }
  }
  // contiguous 64 B per column
  unsigned int* p0 = packed + (size_t)(col0 + 0) * NW + (size_t)jb * 16;
  unsigned int* p1 = packed + (size_t)(col0 + 1) * NW + (size_t)jb * 16;
  unsigned int* p2 = packed + (size_t)(col0 + 2) * NW + (size_t)jb * 16;
  unsigned int* p3 = packed + (size_t)(col0 + 3) * NW + (size_t)jb * 16;
#pragma unroll
  for (int seg = 0; seg < 4; ++seg) *(u32x4*)(p0 + seg * 4) = vv0[seg];
#pragma unroll
  for (int seg = 0; seg < 4; ++seg) *(u32x4*)(p1 + seg * 4) = vv1[seg];
#pragma unroll
  for (int seg = 0; seg < 4; ++seg) *(u32x4*)(p2 + seg * 4) = vv2[seg];
#pragma unroll
  for (int seg = 0; seg < 4; ++seg) *(u32x4*)(p3 + seg * 4) = vv3[seg];

  atomicAdd(&deg[col0 + 0], (float)cnt0);
  atomicAdd(&deg[col0 + 1], (float)cnt1);
  atomicAdd(&deg[col0 + 2], (float)cnt2);
  atomicAdd(&deg[col0 + 3], (float)cnt3);
}

// ---------------------------------------------------------------------------
// K2 (byte-identical to R4/R5): z = dinv*(x@W); z row-major bf16 + chunked z2.
// Z2[jc][f][jj]: 4 KB chunk = 64 features x 32 nodes contiguous.
// ---------------------------------------------------------------------------
__global__ __launch_bounds__(256) void k_z(const float* __restrict__ x,
                                           const float* __restrict__ W,
                                           const float* __restrict__ deg,
                                           float* __restrict__ dinv,
                                           unsigned short* __restrict__ z_rm,
                                           unsigned short* __restrict__ z2) {
  __shared__ float Wl[64][64];
  __shared__ float xl[64][64];
  const int tid = threadIdx.x;
  const int f = tid & 63;
  const int w = tid >> 6;
  const int rowB = blockIdx.x * 64;

  for (int idx = tid; idx < 4096; idx += 256) {
    Wl[idx >> 6][idx & 63] = W[idx];
    xl[idx >> 6][idx & 63] = x[(size_t)rowB * 64 + idx];
  }
  __syncthreads();

  float acc[16];
#pragma unroll
  for (int r = 0; r < 16; ++r) acc[r] = 0.f;
  for (int k = 0; k < 64; ++k) {
    float wk = Wl[k][f];
#pragma unroll
    for (int r = 0; r < 16; ++r) acc[r] = fmaf(xl[w * 16 + r][k], wk, acc[r]);
  }

  const int row0 = rowB + w * 16;
  if (f < 16) {
    int row = row0 + f;
    dinv[row] = 1.0f / sqrtf(deg[row] + 1.0f);
  }

  unsigned short zs[16];
#pragma unroll
  for (int r = 0; r < 16; ++r) {
    int row = row0 + r;
    float di = 1.0f / sqrtf(deg[row] + 1.0f);
    unsigned short zb = f2bf(di * acc[r]);
    zs[r] = zb;
    z_rm[(size_t)row * GF + f] = zb;
  }
  unsigned int p[8];
#pragma unroll
  for (int i = 0; i < 8; ++i)
    p[i] = (unsigned int)zs[2 * i] | ((unsigned int)zs[2 * i + 1] << 16);
  char* dst = (char*)z2 + (size_t)((rowB >> 5) + (w >> 1)) * 4096 + f * 64 + (w & 1) * 32;
  u32x4 lo = {p[0], p[1], p[2], p[3]};
  u32x4 hi = {p[4], p[5], p[6], p[7]};
  *(u32x4*)dst = lo;
  *(u32x4*)(dst + 16) = hi;
}

// ---------------------------------------------------------------------------
// K3 v5: PURE-TLP version of R5. 512 thr = 8 waves = 8 K-EIGHTHS; each wave
// keeps R5's exact per-step profile (4 z-loads + 4 decodes + 16 MFMA, full
// 64x64 tile), 16 iters instead of 32. Per-block z2/bits/decode totals are
// IDENTICAL to R5; only waves/SIMD goes 1 -> 2. Reduction in two phases:
// waves 0-3 write red[4], sync, waves 4-7 +=.
// ---------------------------------------------------------------------------
__global__ __launch_bounds__(512) void k_spmm(const unsigned int* __restrict__ packed,
                                              const unsigned short* __restrict__ z2,
                                              const unsigned short* __restrict__ z_rm,
                                              const float* __restrict__ dinv,
                                              const float* __restrict__ bias,
                                              float* __restrict__ out) {
  __shared__ float red[4][64][64];  // 64 KB
  const int i0 = blockIdx.x * 64;
  const int tid = threadIdx.x;
  const int wid = tid >> 6, lane = tid & 63;
  const int lrow = lane & 15, kb = lane >> 4;
  const int sh = kb * 8;

  f32x4 acc[4][4];
#pragma unroll
  for (int m = 0; m < 4; ++m)
#pragma unroll
    for (int n = 0; n < 4; ++n) acc[m][n] = (f32x4){0.f, 0.f, 0.f, 0.f};

  // wave wid owns k in [wid*2048, (wid+1)*2048): 64 packed dwords, 64 chunks
  const unsigned int* pr0 = packed + (size_t)(i0 + 0 * 16 + lrow) * NW + wid * 64;
  const unsigned int* pr1 = packed + (size_t)(i0 + 1 * 16 + lrow) * NW + wid * 64;
  const unsigned int* pr2 = packed + (size_t)(i0 + 2 * 16 + lrow) * NW + wid * 64;
  const unsigned int* pr3 = packed + (size_t)(i0 + 3 * 16 + lrow) * NW + wid * 64;
  const char* zbase = (const char*)z2 + (size_t)(wid * 64) * 4096 + lrow * 64 + kb * 16;

  // pipeline prologue
  bf16x8 cur0 = *(const bf16x8*)(zbase + 0 * 1024);
  bf16x8 cur1 = *(const bf16x8*)(zbase + 1 * 1024);
  bf16x8 cur2 = *(const bf16x8*)(zbase + 2 * 1024);
  bf16x8 cur3 = *(const bf16x8*)(zbase + 3 * 1024);
  u32x4 bits0 = *(const u32x4*)pr0;
  u32x4 bits1 = *(const u32x4*)pr1;
  u32x4 bits2 = *(const u32x4*)pr2;
  u32x4 bits3 = *(const u32x4*)pr3;

  for (int it = 0; it < 16; ++it) {
    // bits prefetch, one iter ahead (tail read covered by 64 B ws slack)
    u32x4 nb0 = *(const u32x4*)(pr0 + 4);
    u32x4 nb1 = *(const u32x4*)(pr1 + 4);
    u32x4 nb2 = *(const u32x4*)(pr2 + 4);
    u32x4 nb3 = *(const u32x4*)(pr3 + 4);
#pragma unroll
    for (int s = 0; s < 4; ++s) {
      // z prefetch: next chunk (tail lands in adjacent mapped buffer; unused)
      const char* zn = zbase + (s + 1) * 4096;
      bf16x8 n0 = *(const bf16x8*)(zn + 0 * 1024);
      bf16x8 n1 = *(const bf16x8*)(zn + 1 * 1024);
      bf16x8 n2 = *(const bf16x8*)(zn + 2 * 1024);
      bf16x8 n3 = *(const bf16x8*)(zn + 3 * 1024);

      bf16x8 a0 = decode8(bits0[s] >> sh);
      acc[0][0] = __builtin_amdgcn_mfma_f32_16x16x32_bf16(a0, cur0, acc[0][0], 0, 0, 0);
      acc[0][1] = __builtin_amdgcn_mfma_f32_16x16x32_bf16(a0, cur1, acc[0][1], 0, 0, 0);
      acc[0][2] = __builtin_amdgcn_mfma_f32_16x16x32_bf16(a0, cur2, acc[0][2], 0, 0, 0);
      acc[0][3] = __builtin_amdgcn_mfma_f32_16x16x32_bf16(a0, cur3, acc[0][3], 0, 0, 0);
      bf16x8 a1 = decode8(bits1[s] >> sh);
      acc[1][0] = __builtin_amdgcn_mfma_f32_16x16x32_bf16(a1, cur0, acc[1][0], 0, 0, 0);
      acc[1][1] = __builtin_amdgcn_mfma_f32_16x16x32_bf16(a1, cur1, acc[1][1], 0, 0, 0);
      acc[1][2] = __builtin_amdgcn_mfma_f32_16x16x32_bf16(a1, cur2, acc[1][2], 0, 0, 0);
      acc[1][3] = __builtin_amdgcn_mfma_f32_16x16x32_bf16(a1, cur3, acc[1][3], 0, 0, 0);
      bf16x8 a2 = decode8(bits2[s] >> sh);
      acc[2][0] = __builtin_amdgcn_mfma_f32_16x16x32_bf16(a2, cur0, acc[2][0], 0, 0, 0);
      acc[2][1] = __builtin_amdgcn_mfma_f32_16x16x32_bf16(a2, cur1, acc[2][1], 0, 0, 0);
      acc[2][2] = __builtin_amdgcn_mfma_f32_16x16x32_bf16(a2, cur2, acc[2][2], 0, 0, 0);
      acc[2][3] = __builtin_amdgcn_mfma_f32_16x16x32_bf16(a2, cur3, acc[2][3], 0, 0, 0);
      bf16x8 a3 = decode8(bits3[s] >> sh);
      acc[3][0] = __builtin_amdgcn_mfma_f32_16x16x32_bf16(a3, cur0, acc[3][0], 0, 0, 0);
      acc[3][1] = __builtin_amdgcn_mfma_f32_16x16x32_bf16(a3, cur1, acc[3][1], 0, 0, 0);
      acc[3][2] = __builtin_amdgcn_mfma_f32_16x16x32_bf16(a3, cur2, acc[3][2], 0, 0, 0);
      acc[3][3] = __builtin_amdgcn_mfma_f32_16x16x32_bf16(a3, cur3, acc[3][3], 0, 0, 0);

      cur0 = n0; cur1 = n1; cur2 = n2; cur3 = n3;
    }
    bits0 = nb0; bits1 = nb1; bits2 = nb2; bits3 = nb3;
    pr0 += 4; pr1 += 4; pr2 += 4; pr3 += 4;
    zbase += 16384;  // 4 chunks
  }

  // two-phase split-K reduction: row = m*16 + kb*4 + r, col = n*16 + lrow
  if (wid < 4) {
#pragma unroll
    for (int m = 0; m < 4; ++m)
#pragma unroll
      for (int n = 0; n < 4; ++n)
#pragma unroll
        for (int r = 0; r < 4; ++r)
          red[wid][m * 16 + kb * 4 + r][n * 16 + lrow] = acc[m][n][r];
  }
  __syncthreads();
  if (wid >= 4) {
#pragma unroll
    for (int m = 0; m < 4; ++m)
#pragma unroll
      for (int n = 0; n < 4; ++n)
#pragma unroll
        for (int r = 0; r < 4; ++r)
          red[wid - 4][m * 16 + kb * 4 + r][n * 16 + lrow] += acc[m][n][r];
  }
  __syncthreads();

  // epilogue: reduce 4 partials, add self-loop z, scale, bias, relu
  const int c = tid & 63;
  const int rg = tid >> 6;  // 0..7
  const float bc = bias[c];
#pragma unroll
  for (int rr = 0; rr < 8; ++rr) {
    int r = rg * 8 + rr;
    int i = i0 + r;
    float s = red[0][r][c] + red[1][r][c] + red[2][r][c] + red[3][r][c];
    float o = dinv[i] * (s + bf2f(z_rm[(size_t)i * GF + c])) + bc;
    out[(size_t)i * GF + c] = fmaxf(o, 0.f);
  }
}

// ---------------------------------------------------------------------------
extern "C" void kernel_launch(void* const* d_in, const int* in_sizes, int n_in,
                              void* d_out, int out_size, void* d_ws, size_t ws_size,
                              hipStream_t stream) {
  const float* x = (const float*)d_in[0];
  const float* adj = (const float*)d_in[1];
  const float* W = (const float*)d_in[2];
  const float* bias = (const float*)d_in[3];
  float* out = (float*)d_out;

  char* ws = (char*)d_ws;
  float* deg = (float*)ws;                                        // 64 KB
  float* dinv = (float*)(ws + 65536);                             // 64 KB
  unsigned short* z_rm = (unsigned short*)(ws + 131072);          // 2 MB
  unsigned short* z2 = (unsigned short*)(ws + 131072 + 2097152);  // 2 MB chunk-tiled
  unsigned int* packed = (unsigned int*)(ws + 131072 + 4194304);  // 32 MB + 64 B slack
  if (ws_size < 37879872u) return;

  hipMemsetAsync(deg, 0, GN * sizeof(float), stream);
  k_pack<<<dim3(512), dim3(256), 0, stream>>>(adj, deg, packed);
  k_z<<<dim3(GN / 64), dim3(256), 0, stream>>>(x, W, deg, dinv, z_rm, z2);
  k_spmm<<<dim3(GN / 64), dim3(512), 0, stream>>>(packed, z2, z_rm, dinv, bias, out);
}